// Round 5
// baseline (195.567 us; speedup 1.0000x reference)
//
#include <hip/hip_runtime.h>
#include <hip/hip_bf16.h>

// ---------------------------------------------------------------------------
// CrossRNN: embed-gather -> 2-layer Elman RNN (relu) -> row/col cross -> dot
// B=4 R=64 C=64 S=32 V=30000 E=H=128 L=2   N = 16384 sequences
//
// Architecture (round 5): barrier-free-in-spirit RNN — one wave owns 16 seqs
// x full H=128. MFMA roles: A = weight frags (row = h-out), B = h (col = seq).
// All 3 weight matrices in wave-private registers (384 regs; AGPR+VGPR).
// D->B fragment conversion via wave-private 4KB LDS slab; ALL fences are
// __syncthreads() (one-wave block => just a waitcnt drain, compiler-blessed;
// round 4's hand-rolled asm fences produced NaN). No inline asm anywhere.
//
//  k_wprep: Wb[4][128][128] bf16 = {Whh0, Wih1, Whh1, Wih0}
//  k_t1p  : T1p[v] = bf16(embed[v]·Wih0^T + b_ih0 + b_hh0), lane-permuted
//           uint j = lg*16 + 2m + p  holds h = {16m+4lg+2p, +1}
//  k_rnn  : fused 2-layer RNN, 96 MFMA/step/wave, slab conversion
//  k_final: out = s1 + rowsum(s2) + colsum(s2) - 2*s2 + pred_b
// ---------------------------------------------------------------------------

typedef __attribute__((ext_vector_type(8))) short short8;
typedef __attribute__((ext_vector_type(4))) float f32x4;
typedef __attribute__((ext_vector_type(2))) unsigned int u32x2;
typedef __attribute__((ext_vector_type(4))) unsigned int u32x4;

#define Hd 128
#define Sd 32
#define VROWS 30000

__device__ __forceinline__ unsigned short f2b(float f) {
  __hip_bfloat16 h = __float2bfloat16(f);
  return reinterpret_cast<unsigned short&>(h);
}
__device__ __forceinline__ unsigned int pack2(float a, float b) {
  return (unsigned int)f2b(a) | ((unsigned int)f2b(b) << 16);
}
__device__ __forceinline__ float blo(unsigned int u) { return __uint_as_float(u << 16); }
__device__ __forceinline__ float bhi(unsigned int u) { return __uint_as_float(u & 0xffff0000u); }

__device__ __forceinline__ f32x4 mfma16(short8 a, short8 b, f32x4 c) {
  return __builtin_amdgcn_mfma_f32_16x16x32_bf16(a, b, c, 0, 0, 0);
}

// load 8 consecutive f32 (32B aligned) -> bf16 fragment
__device__ __forceinline__ short8 load_row8_bf16(const float* __restrict__ p) {
  const float4* q = reinterpret_cast<const float4*>(p);
  float4 a = q[0], b = q[1];
  short8 s;
  s[0] = (short)f2b(a.x); s[1] = (short)f2b(a.y);
  s[2] = (short)f2b(a.z); s[3] = (short)f2b(a.w);
  s[4] = (short)f2b(b.x); s[5] = (short)f2b(b.y);
  s[6] = (short)f2b(b.z); s[7] = (short)f2b(b.w);
  return s;
}

// ---------------------------------------------------------------------------
// K0: weights -> bf16 once. Wb: [0]=W_hh[0], [1]=W_ih[1], [2]=W_hh[1], [3]=W_ih[0]
// ---------------------------------------------------------------------------
__global__ __launch_bounds__(1024) void k_wprep(const float* __restrict__ W_ih,
                                                const float* __restrict__ W_hh,
                                                unsigned short* __restrict__ Wb) {
  int i = blockIdx.x * 1024 + threadIdx.x;  // 0..65535
  int m = i >> 14, r = i & 16383;
  float f = (m == 0) ? W_hh[r]
          : (m == 1) ? W_ih[16384 + r]
          : (m == 2) ? W_hh[16384 + r]
                     : W_ih[r];
  Wb[i] = f2b(f);
}

// ---------------------------------------------------------------------------
// K1: T1p (bf16, permuted, both layer-0 biases folded). 160 blocks x 256 thr.
// (256,1): ~235 VGPR working set must NOT be capped to 128 (round-3 lesson).
// ---------------------------------------------------------------------------
__global__ __launch_bounds__(256, 1) void k_t1p(const float* __restrict__ embed,
                                                const unsigned short* __restrict__ Wb,
                                                const float* __restrict__ b_ih,
                                                const float* __restrict__ b_hh,
                                                unsigned int* __restrict__ T1p) {
  const int tid = threadIdx.x, lane = tid & 63, wid = tid >> 6;
  const int l15 = lane & 15, lg = lane >> 4;
  const int gw = blockIdx.x * 4 + wid;  // 0..639

  short8 Wf[8][4];
  f32x4 biasD[8];
  const unsigned short* W0 = Wb + 3 * 16384;
#pragma unroll
  for (int m = 0; m < 8; ++m) {
#pragma unroll
    for (int kt = 0; kt < 4; ++kt)
      Wf[m][kt] = *reinterpret_cast<const short8*>(W0 + (16 * m + l15) * Hd + 32 * kt + 8 * lg);
    const float4 bi = *reinterpret_cast<const float4*>(b_ih + 16 * m + 4 * lg);
    const float4 bh = *reinterpret_cast<const float4*>(b_hh + 16 * m + 4 * lg);
    biasD[m] = (f32x4){bi.x + bh.x, bi.y + bh.y, bi.z + bh.z, bi.w + bh.w};
  }

  for (int tt = gw; tt < 1875; tt += 640) {
    const int v = tt * 16 + l15;
    short8 Ef[4];
#pragma unroll
    for (int kt = 0; kt < 4; ++kt)
      Ef[kt] = load_row8_bf16(embed + (size_t)v * Hd + 32 * kt + 8 * lg);
    f32x4 acc[8];
#pragma unroll
    for (int m = 0; m < 8; ++m) acc[m] = biasD[m];
#pragma unroll
    for (int kt = 0; kt < 4; ++kt)
#pragma unroll
      for (int m = 0; m < 8; ++m) acc[m] = mfma16(Wf[m][kt], Ef[kt], acc[m]);
    unsigned int dw[16];
#pragma unroll
    for (int m = 0; m < 8; ++m) {
      dw[2 * m]     = pack2(acc[m][0], acc[m][1]);
      dw[2 * m + 1] = pack2(acc[m][2], acc[m][3]);
    }
    unsigned int* dst = T1p + (size_t)v * 64 + lg * 16;
#pragma unroll
    for (int j = 0; j < 4; ++j)
      *reinterpret_cast<u32x4*>(dst + 4 * j) =
          (u32x4){dw[4 * j], dw[4 * j + 1], dw[4 * j + 2], dw[4 * j + 3]};
  }
}

// ---------------------------------------------------------------------------
// K2: fused RNN. 1024 blocks x 64 threads (ONE wave per block).
// slab layout: [0:4096)=h1, [4096:8192)=h2; row = seq (l15), 256B/row,
// byte within row = (2*h) ^ (l15<<4)  (bank-spreading involution).
// ---------------------------------------------------------------------------
__global__ __launch_bounds__(64) void k_rnn(const int* __restrict__ x,
                                            const unsigned int* __restrict__ T1p,
                                            const unsigned short* __restrict__ Wb,
                                            const float* __restrict__ b_ih,
                                            const float* __restrict__ b_hh,
                                            const float* __restrict__ pred_W,
                                            float* __restrict__ sbuf) {
  __shared__ alignas(16) unsigned char slab[8192];
  __shared__ int xs[528];  // [16][33] bank-spread

  const int lane = threadIdx.x & 63, l15 = lane & 15, lg = (lane >> 4) & 3;
  const int seq0 = blockIdx.x * 16;

  // stage x indices: xs[seq][t] at seq*33+t
#pragma unroll
  for (int k = 0; k < 8; ++k) {
    int e = lane * 8 + k;
    xs[(e >> 5) * 33 + (e & 31)] = x[(size_t)seq0 * Sd + e];
  }

  // full weight set in registers (A-frags: row = h_out, k = h_in)
  short8 Wh0[8][4], Wi1[8][4], Wh1[8][4];
#pragma unroll
  for (int m = 0; m < 8; ++m)
#pragma unroll
    for (int kt = 0; kt < 4; ++kt) {
      const int o = (16 * m + l15) * Hd + 32 * kt + 8 * lg;
      Wh0[m][kt] = *reinterpret_cast<const short8*>(Wb + o);
      Wi1[m][kt] = *reinterpret_cast<const short8*>(Wb + 16384 + o);
      Wh1[m][kt] = *reinterpret_cast<const short8*>(Wb + 32768 + o);
    }
  // layer-1 bias, packed bf16 in D-pattern (h = 16m+4lg+r)
  unsigned int bsumP[16];
#pragma unroll
  for (int m = 0; m < 8; ++m) {
    const float4 bi = *reinterpret_cast<const float4*>(b_ih + Hd + 16 * m + 4 * lg);
    const float4 bh = *reinterpret_cast<const float4*>(b_hh + Hd + 16 * m + 4 * lg);
    bsumP[2 * m]     = pack2(bi.x + bh.x, bi.y + bh.y);
    bsumP[2 * m + 1] = pack2(bi.z + bh.z, bi.w + bh.w);
  }
  // slab addresses (loop-invariant)
  int wb_[8], rb_[4];
#pragma unroll
  for (int m = 0; m < 8; ++m) wb_[m] = l15 * 256 + ((32 * m + 8 * lg) ^ (l15 << 4));
#pragma unroll
  for (int kt = 0; kt < 4; ++kt) rb_[kt] = l15 * 256 + ((64 * kt + 16 * lg) ^ (l15 << 4));

  __syncthreads();  // xs visible

  short8 h1f[4], h2f[4];
  f32x4 acc[8];
  u32x4 t1q[4];

  // ---- t=0: h1_0 = relu(t1_0)  (t1 already includes b_ih0 + b_hh0)
  {
    int i0 = xs[l15 * 33 + 0];
    const u32x4* tp = reinterpret_cast<const u32x4*>(T1p + (size_t)i0 * 64 + lg * 16);
    t1q[0] = tp[0]; t1q[1] = tp[1]; t1q[2] = tp[2]; t1q[3] = tp[3];
  }
#pragma unroll
  for (int m = 0; m < 8; ++m) {
    unsigned int qa = t1q[(2 * m) >> 2][(2 * m) & 3];
    unsigned int qb = t1q[(2 * m + 1) >> 2][(2 * m + 1) & 3];
    float a0 = fmaxf(blo(qa), 0.f), a1 = fmaxf(bhi(qa), 0.f);
    float a2 = fmaxf(blo(qb), 0.f), a3 = fmaxf(bhi(qb), 0.f);
    u32x2 w; w[0] = pack2(a0, a1); w[1] = pack2(a2, a3);
    *reinterpret_cast<u32x2*>(slab + wb_[m]) = w;
  }
  __syncthreads();
#pragma unroll
  for (int kt = 0; kt < 4; ++kt)
    h1f[kt] = *reinterpret_cast<const short8*>(slab + rb_[kt]);
  // prefetch t1(1)
  {
    int i1 = xs[l15 * 33 + 1];
    const u32x4* tp = reinterpret_cast<const u32x4*>(T1p + (size_t)i1 * 64 + lg * 16);
    t1q[0] = tp[0]; t1q[1] = tp[1]; t1q[2] = tp[2]; t1q[3] = tp[3];
  }
  // ---- L2(0): h2_0 = relu(bsum + Wi1·h1_0)
#pragma unroll
  for (int m = 0; m < 8; ++m) {
    acc[m][0] = blo(bsumP[2 * m]);     acc[m][1] = bhi(bsumP[2 * m]);
    acc[m][2] = blo(bsumP[2 * m + 1]); acc[m][3] = bhi(bsumP[2 * m + 1]);
  }
#pragma unroll
  for (int kt = 0; kt < 4; ++kt)
#pragma unroll
    for (int m = 0; m < 8; ++m) acc[m] = mfma16(Wi1[m][kt], h1f[kt], acc[m]);
#pragma unroll
  for (int m = 0; m < 8; ++m) {
    float a0 = fmaxf(acc[m][0], 0.f), a1 = fmaxf(acc[m][1], 0.f);
    float a2 = fmaxf(acc[m][2], 0.f), a3 = fmaxf(acc[m][3], 0.f);
    u32x2 w; w[0] = pack2(a0, a1); w[1] = pack2(a2, a3);
    *reinterpret_cast<u32x2*>(slab + 4096 + wb_[m]) = w;
  }
  __syncthreads();
#pragma unroll
  for (int kt = 0; kt < 4; ++kt)
    h2f[kt] = *reinterpret_cast<const short8*>(slab + 4096 + rb_[kt]);

  // ---- t = 1..31
#pragma unroll 1
  for (int t = 1; t < Sd; ++t) {
    // L1: h1_t = relu(Wh0·h1_{t-1} + t1_t)
#pragma unroll
    for (int m = 0; m < 8; ++m)
      acc[m] = mfma16(Wh0[m][0], h1f[0], (f32x4){0.f, 0.f, 0.f, 0.f});
#pragma unroll
    for (int kt = 1; kt < 4; ++kt)
#pragma unroll
      for (int m = 0; m < 8; ++m) acc[m] = mfma16(Wh0[m][kt], h1f[kt], acc[m]);
#pragma unroll
    for (int m = 0; m < 8; ++m) {
      unsigned int qa = t1q[(2 * m) >> 2][(2 * m) & 3];
      unsigned int qb = t1q[(2 * m + 1) >> 2][(2 * m + 1) & 3];
      float a0 = fmaxf(acc[m][0] + blo(qa), 0.f), a1 = fmaxf(acc[m][1] + bhi(qa), 0.f);
      float a2 = fmaxf(acc[m][2] + blo(qb), 0.f), a3 = fmaxf(acc[m][3] + bhi(qb), 0.f);
      u32x2 w; w[0] = pack2(a0, a1); w[1] = pack2(a2, a3);
      *reinterpret_cast<u32x2*>(slab + wb_[m]) = w;
    }
    __syncthreads();
#pragma unroll
    for (int kt = 0; kt < 4; ++kt)
      h1f[kt] = *reinterpret_cast<const short8*>(slab + rb_[kt]);
    // prefetch t1 for t+1 (clamped; consumed next iteration's L1 epilogue)
    {
      int tn = (t < 31) ? t + 1 : 31;
      int ix = xs[l15 * 33 + tn];
      const u32x4* tp = reinterpret_cast<const u32x4*>(T1p + (size_t)ix * 64 + lg * 16);
      t1q[0] = tp[0]; t1q[1] = tp[1]; t1q[2] = tp[2]; t1q[3] = tp[3];
    }
    // L2: h2_t = relu(bsum + Wi1·h1_t + Wh1·h2_{t-1})
#pragma unroll
    for (int m = 0; m < 8; ++m) {
      acc[m][0] = blo(bsumP[2 * m]);     acc[m][1] = bhi(bsumP[2 * m]);
      acc[m][2] = blo(bsumP[2 * m + 1]); acc[m][3] = bhi(bsumP[2 * m + 1]);
    }
#pragma unroll
    for (int kt = 0; kt < 4; ++kt) {
#pragma unroll
      for (int m = 0; m < 8; ++m) acc[m] = mfma16(Wi1[m][kt], h1f[kt], acc[m]);
#pragma unroll
      for (int m = 0; m < 8; ++m) acc[m] = mfma16(Wh1[m][kt], h2f[kt], acc[m]);
    }
    if (t < 31) {
#pragma unroll
      for (int m = 0; m < 8; ++m) {
        float a0 = fmaxf(acc[m][0], 0.f), a1 = fmaxf(acc[m][1], 0.f);
        float a2 = fmaxf(acc[m][2], 0.f), a3 = fmaxf(acc[m][3], 0.f);
        u32x2 w; w[0] = pack2(a0, a1); w[1] = pack2(a2, a3);
        *reinterpret_cast<u32x2*>(slab + 4096 + wb_[m]) = w;
      }
      __syncthreads();
#pragma unroll
      for (int kt = 0; kt < 4; ++kt)
        h2f[kt] = *reinterpret_cast<const short8*>(slab + 4096 + rb_[kt]);
    }
  }

  // ---- epilogue: acc = pre-relu h2_31 (D-layout: h = 16m+4lg+r, seq = l15)
  float p1 = 0.f, p2 = 0.f;
#pragma unroll
  for (int m = 0; m < 8; ++m) {
    const float4 w1 = *reinterpret_cast<const float4*>(pred_W + 16 * m + 4 * lg);
    const float4 w2 = *reinterpret_cast<const float4*>(pred_W + Hd + 16 * m + 4 * lg);
    float a0 = fmaxf(acc[m][0], 0.f), a1 = fmaxf(acc[m][1], 0.f);
    float a2 = fmaxf(acc[m][2], 0.f), a3 = fmaxf(acc[m][3], 0.f);
    p1 += a0 * w1.x + a1 * w1.y + a2 * w1.z + a3 * w1.w;
    p2 += a0 * w2.x + a1 * w2.y + a2 * w2.z + a3 * w2.w;
  }
  p1 += __shfl_xor(p1, 16); p1 += __shfl_xor(p1, 32);
  p2 += __shfl_xor(p2, 16); p2 += __shfl_xor(p2, 32);
  if (lane < 16) {
    sbuf[seq0 + lane] = p1;
    sbuf[16384 + seq0 + lane] = p2;
  }
}

// ---------------------------------------------------------------------------
// K3: out[b,r,c] = s1 + rowsum_c(s2) + colsum_r(s2) - 2*s2 + pred_b
// ---------------------------------------------------------------------------
__global__ __launch_bounds__(1024) void k_final(const float* __restrict__ sbuf,
                                                const float* __restrict__ pred_b,
                                                float* __restrict__ out) {
  __shared__ float s2s[64][65];
  __shared__ float rowS[64], colS[64];
  const int b = blockIdx.x, tid = threadIdx.x;
  const float* s1g = sbuf + b * 4096;
  const float* s2g = sbuf + 16384 + b * 4096;
#pragma unroll
  for (int i = 0; i < 4; ++i) {
    int j = tid + i * 1024;
    s2s[j >> 6][j & 63] = s2g[j];
  }
  __syncthreads();
  if (tid < 64) {
    float s = 0.f;
    for (int cc = 0; cc < 64; ++cc) s += s2s[tid][cc];
    rowS[tid] = s;
  } else if (tid < 128) {
    int cc = tid - 64;
    float s = 0.f;
    for (int r = 0; r < 64; ++r) s += s2s[r][cc];
    colS[cc] = s;
  }
  __syncthreads();
  const float pb = pred_b[0];
#pragma unroll
  for (int i = 0; i < 4; ++i) {
    int j = tid + i * 1024;
    int r = j >> 6, cc = j & 63;
    out[b * 4096 + j] = s1g[j] + rowS[r] + colS[cc] - 2.f * s2s[r][cc] + pb;
  }
}

// ---------------------------------------------------------------------------
extern "C" void kernel_launch(void* const* d_in, const int* in_sizes, int n_in,
                              void* d_out, int out_size, void* d_ws,
                              size_t ws_size, hipStream_t stream) {
  const int* x = (const int*)d_in[0];
  const float* embed = (const float*)d_in[1];
  const float* W_ih = (const float*)d_in[2];
  const float* W_hh = (const float*)d_in[3];
  const float* b_ih = (const float*)d_in[4];
  const float* b_hh = (const float*)d_in[5];
  const float* pred_W = (const float*)d_in[6];
  const float* pred_b = (const float*)d_in[7];

  // ws layout: T1p (7,680,000 B) | Wb (131,072 B) | sbuf (131,072 B)
  unsigned int* T1p = (unsigned int*)d_ws;
  unsigned short* Wb = (unsigned short*)((char*)d_ws + (size_t)VROWS * 256);
  float* sbuf = (float*)((char*)d_ws + (size_t)VROWS * 256 + 131072);
  float* out = (float*)d_out;

  k_wprep<<<64, 1024, 0, stream>>>(W_ih, W_hh, Wb);
  k_t1p<<<160, 256, 0, stream>>>(embed, Wb, b_ih, b_hh, T1p);
  k_rnn<<<1024, 64, 0, stream>>>(x, T1p, Wb, b_ih, b_hh, pred_W, sbuf);
  k_final<<<4, 1024, 0, stream>>>(sbuf, pred_b, out);
}

// Round 6
// 146.596 us; speedup vs baseline: 1.3340x; 1.3340x over previous
//
#include <hip/hip_runtime.h>
#include <hip/hip_bf16.h>

// ---------------------------------------------------------------------------
// CrossRNN: embed-gather -> 2-layer Elman RNN (relu) -> row/col cross -> dot
// B=4 R=64 C=64 S=32 V=30000 E=H=128 L=2   N = 16384 sequences
//
// Round-6: A=weights / B=h MFMA roles, 4 waves/block (M=32 per wave),
// 32 seqs/block (2 B-tiles), 512 blocks -- ALL resident (8 waves/CU, 2/SIMD).
// Cross-wave h exchange via raw s_barrier + lgkmcnt(0) (round-3-proven; does
// NOT drain vmcnt -> T1p gather prefetch stays in flight across barriers).
// Weights self-converted f32->bf16 in each kernel's prologue (no k_wprep).
//
//  k_t1p  : T1p[v] = bf16(embed[v]·Wih0^T + b_ih0 + b_hh0), lane-permuted
//           uint j = 16*lg + 2m + p  holds h = {16m+4lg+2p, +1}
//  k_rnn  : fused 2-layer RNN, 48 MFMA/wave/step, 2 barriers/step
//  k_final: out = s1 + rowsum(s2) + colsum(s2) - 2*s2 + pred_b
// ---------------------------------------------------------------------------

typedef __attribute__((ext_vector_type(8))) short short8;
typedef __attribute__((ext_vector_type(4))) float f32x4;
typedef __attribute__((ext_vector_type(2))) unsigned int u32x2;
typedef __attribute__((ext_vector_type(4))) unsigned int u32x4;

#define Hd 128
#define Sd 32
#define VROWS 30000

__device__ __forceinline__ unsigned short f2b(float f) {
  __hip_bfloat16 h = __float2bfloat16(f);
  return reinterpret_cast<unsigned short&>(h);
}
__device__ __forceinline__ unsigned int pack2(float a, float b) {
  return (unsigned int)f2b(a) | ((unsigned int)f2b(b) << 16);
}
__device__ __forceinline__ float blo(unsigned int u) { return __uint_as_float(u << 16); }
__device__ __forceinline__ float bhi(unsigned int u) { return __uint_as_float(u & 0xffff0000u); }

__device__ __forceinline__ f32x4 mfma16(short8 a, short8 b, f32x4 c) {
  return __builtin_amdgcn_mfma_f32_16x16x32_bf16(a, b, c, 0, 0, 0);
}

// load 8 consecutive f32 (32B aligned) -> bf16 fragment
__device__ __forceinline__ short8 load_row8_bf16(const float* __restrict__ p) {
  const float4* q = reinterpret_cast<const float4*>(p);
  float4 a = q[0], b = q[1];
  short8 s;
  s[0] = (short)f2b(a.x); s[1] = (short)f2b(a.y);
  s[2] = (short)f2b(a.z); s[3] = (short)f2b(a.w);
  s[4] = (short)f2b(b.x); s[5] = (short)f2b(b.y);
  s[6] = (short)f2b(b.z); s[7] = (short)f2b(b.w);
  return s;
}

// ---------------------------------------------------------------------------
// K1: T1p (bf16, permuted, both layer-0 biases folded). 256 blocks x 256 thr;
// each wave self-converts Wih0 (L2-resident reads) and does ~2 v-tiles.
// ---------------------------------------------------------------------------
__global__ __launch_bounds__(256, 1) void k_t1p(const float* __restrict__ embed,
                                                const float* __restrict__ W_ih,
                                                const float* __restrict__ b_ih,
                                                const float* __restrict__ b_hh,
                                                unsigned int* __restrict__ T1p) {
  const int tid = threadIdx.x, lane = tid & 63, wid = tid >> 6;
  const int l15 = lane & 15, lg = lane >> 4;
  const int gw = blockIdx.x * 4 + wid;  // 0..1023

  short8 Wf[8][4];
  f32x4 biasD[8];
#pragma unroll
  for (int m = 0; m < 8; ++m) {
#pragma unroll
    for (int kt = 0; kt < 4; ++kt)
      Wf[m][kt] = load_row8_bf16(W_ih + (16 * m + l15) * Hd + 32 * kt + 8 * lg);
    const float4 bi = *reinterpret_cast<const float4*>(b_ih + 16 * m + 4 * lg);
    const float4 bh = *reinterpret_cast<const float4*>(b_hh + 16 * m + 4 * lg);
    biasD[m] = (f32x4){bi.x + bh.x, bi.y + bh.y, bi.z + bh.z, bi.w + bh.w};
  }

  for (int tt = gw; tt < 1875; tt += 1024) {
    const int v = tt * 16 + l15;
    short8 Ef[4];
#pragma unroll
    for (int kt = 0; kt < 4; ++kt)
      Ef[kt] = load_row8_bf16(embed + (size_t)v * Hd + 32 * kt + 8 * lg);
    f32x4 acc[8];
#pragma unroll
    for (int m = 0; m < 8; ++m) acc[m] = biasD[m];
#pragma unroll
    for (int kt = 0; kt < 4; ++kt)
#pragma unroll
      for (int m = 0; m < 8; ++m) acc[m] = mfma16(Wf[m][kt], Ef[kt], acc[m]);
    unsigned int dw[16];
#pragma unroll
    for (int m = 0; m < 8; ++m) {
      dw[2 * m]     = pack2(acc[m][0], acc[m][1]);
      dw[2 * m + 1] = pack2(acc[m][2], acc[m][3]);
    }
    unsigned int* dst = T1p + (size_t)v * 64 + lg * 16;
#pragma unroll
    for (int j = 0; j < 4; ++j)
      *reinterpret_cast<u32x4*>(dst + 4 * j) =
          (u32x4){dw[4 * j], dw[4 * j + 1], dw[4 * j + 2], dw[4 * j + 3]};
  }
}

// ---------------------------------------------------------------------------
// K2: fused RNN. 512 blocks x 256 thr (4 waves). Wave ws owns output dims
// [32ws, 32ws+32) (2 M-tiles); 32 seqs/block (2 B-tiles: s = bt*16 + l15).
// slab[st]: 32 rows(seq) x 256B; byte = row*256 + ((2h) ^ ((row&15)<<4)).
// ---------------------------------------------------------------------------
__global__ __launch_bounds__(256, 2) void k_rnn(
    const int* __restrict__ x, const unsigned int* __restrict__ T1p,
    const float* __restrict__ W_ih, const float* __restrict__ W_hh,
    const float* __restrict__ b_ih, const float* __restrict__ b_hh,
    const float* __restrict__ pred_W, float* __restrict__ sbuf) {
  __shared__ alignas(16) unsigned char slab[2][8192];
  __shared__ int xs[32 * 33 + 16];
  __shared__ float sred[4][32][2];

  const int tid = threadIdx.x, lane = tid & 63, ws = tid >> 6;
  const int l15 = lane & 15, lg = lane >> 4;
  const int seq0 = blockIdx.x * 32;

  // stage xs: xs[s][t] at s*33+t (1024 ints)
#pragma unroll
  for (int k = 0; k < 4; ++k) {
    int e = tid + k * 256;  // e = s*32 + t
    xs[(e >> 5) * 33 + (e & 31)] = x[(size_t)seq0 * Sd + e];
  }
  if (tid < 32) xs[tid * 33 + 32] = 0;  // t=32 prefetch pad
  __syncthreads();

  const int s0 = l15, s1 = l15 + 16;    // local seqs (bt=0,1)
  const int jbase = 16 * lg + 4 * ws;   // T1p uint col for h=32ws+16mt+4lg+..

  // t1q[bt][mt]: issue t=0 gather early (covered by weight-convert VALU)
  u32x2 t1q[2][2];
  {
    int i0 = xs[s0 * 33 + 0], i1 = xs[s1 * 33 + 0];
    const u32x2* p0 = reinterpret_cast<const u32x2*>(T1p + (size_t)i0 * 64 + jbase);
    const u32x2* p1 = reinterpret_cast<const u32x2*>(T1p + (size_t)i1 * 64 + jbase);
    t1q[0][0] = p0[0]; t1q[0][1] = p0[1];
    t1q[1][0] = p1[0]; t1q[1][1] = p1[1];
  }

  // weights (A-frags: row = h_out within tile = l15, k-slice = 32kt+8lg)
  short8 Wh0[2][4], Wi1[2][4], Wh1[2][4];
#pragma unroll
  for (int mt = 0; mt < 2; ++mt)
#pragma unroll
    for (int kt = 0; kt < 4; ++kt) {
      const int ro = (32 * ws + 16 * mt + l15) * Hd + 32 * kt + 8 * lg;
      Wh0[mt][kt] = load_row8_bf16(W_hh + ro);
      Wi1[mt][kt] = load_row8_bf16(W_ih + 16384 + ro);
      Wh1[mt][kt] = load_row8_bf16(W_hh + 16384 + ro);
    }
  // layer-1 bias, packed bf16 in D-pattern (h = 32ws+16mt+4lg+r)
  u32x2 bsumP[2];
#pragma unroll
  for (int mt = 0; mt < 2; ++mt) {
    const float4 bi = *reinterpret_cast<const float4*>(b_ih + Hd + 32 * ws + 16 * mt + 4 * lg);
    const float4 bh = *reinterpret_cast<const float4*>(b_hh + Hd + 32 * ws + 16 * mt + 4 * lg);
    bsumP[mt][0] = pack2(bi.x + bh.x, bi.y + bh.y);
    bsumP[mt][1] = pack2(bi.z + bh.z, bi.w + bh.w);
  }
  // slab offsets (loop-invariant)
  int wb[2][2], rb[2][4];
#pragma unroll
  for (int bt = 0; bt < 2; ++bt) {
#pragma unroll
    for (int mt = 0; mt < 2; ++mt)
      wb[bt][mt] = bt * 4096 + l15 * 256 + ((64 * ws + 32 * mt + 8 * lg) ^ (l15 << 4));
#pragma unroll
    for (int kt = 0; kt < 4; ++kt)
      rb[bt][kt] = bt * 4096 + l15 * 256 + ((64 * kt + 16 * lg) ^ (l15 << 4));
  }

  short8 h1f[2][4], h2f[2][4];
  f32x4 acc[2][2];  // [mt][bt]

  // ---- t=0: h1_0 = relu(t1_0)   (t1 includes b_ih0 + b_hh0)
#pragma unroll
  for (int bt = 0; bt < 2; ++bt)
#pragma unroll
    for (int mt = 0; mt < 2; ++mt) {
      u32x2 q = t1q[bt][mt];
      float a0 = fmaxf(blo(q[0]), 0.f), a1 = fmaxf(bhi(q[0]), 0.f);
      float a2 = fmaxf(blo(q[1]), 0.f), a3 = fmaxf(bhi(q[1]), 0.f);
      u32x2 w; w[0] = pack2(a0, a1); w[1] = pack2(a2, a3);
      *reinterpret_cast<u32x2*>(slab[0] + wb[bt][mt]) = w;
    }
  // prefetch t1(1)
  {
    int i0 = xs[s0 * 33 + 1], i1 = xs[s1 * 33 + 1];
    const u32x2* p0 = reinterpret_cast<const u32x2*>(T1p + (size_t)i0 * 64 + jbase);
    const u32x2* p1 = reinterpret_cast<const u32x2*>(T1p + (size_t)i1 * 64 + jbase);
    t1q[0][0] = p0[0]; t1q[0][1] = p0[1];
    t1q[1][0] = p1[0]; t1q[1][1] = p1[1];
  }
  asm volatile("s_waitcnt lgkmcnt(0)" ::: "memory");
  __builtin_amdgcn_s_barrier();
#pragma unroll
  for (int bt = 0; bt < 2; ++bt)
#pragma unroll
    for (int kt = 0; kt < 4; ++kt)
      h1f[bt][kt] = *reinterpret_cast<const short8*>(slab[0] + rb[bt][kt]);

  // ---- L2(0): h2_0 = relu(bsum + Wi1·h1_0)
#pragma unroll
  for (int mt = 0; mt < 2; ++mt)
#pragma unroll
    for (int bt = 0; bt < 2; ++bt)
      acc[mt][bt] = (f32x4){blo(bsumP[mt][0]), bhi(bsumP[mt][0]),
                            blo(bsumP[mt][1]), bhi(bsumP[mt][1])};
#pragma unroll
  for (int kt = 0; kt < 4; ++kt)
#pragma unroll
    for (int mt = 0; mt < 2; ++mt)
#pragma unroll
      for (int bt = 0; bt < 2; ++bt)
        acc[mt][bt] = mfma16(Wi1[mt][kt], h1f[bt][kt], acc[mt][bt]);
#pragma unroll
  for (int bt = 0; bt < 2; ++bt)
#pragma unroll
    for (int mt = 0; mt < 2; ++mt) {
      f32x4 a = acc[mt][bt];
      u32x2 w;
      w[0] = pack2(fmaxf(a[0], 0.f), fmaxf(a[1], 0.f));
      w[1] = pack2(fmaxf(a[2], 0.f), fmaxf(a[3], 0.f));
      *reinterpret_cast<u32x2*>(slab[1] + wb[bt][mt]) = w;
    }
  asm volatile("s_waitcnt lgkmcnt(0)" ::: "memory");
  __builtin_amdgcn_s_barrier();
#pragma unroll
  for (int bt = 0; bt < 2; ++bt)
#pragma unroll
    for (int kt = 0; kt < 4; ++kt)
      h2f[bt][kt] = *reinterpret_cast<const short8*>(slab[1] + rb[bt][kt]);

  // ---- t = 1..31
#pragma unroll 1
  for (int t = 1; t < Sd; ++t) {
    // phase A: h1_t = relu(Wh0·h1_{t-1} + t1_t)
#pragma unroll
    for (int mt = 0; mt < 2; ++mt)
#pragma unroll
      for (int bt = 0; bt < 2; ++bt)
        acc[mt][bt] = mfma16(Wh0[mt][0], h1f[bt][0], (f32x4){0.f, 0.f, 0.f, 0.f});
#pragma unroll
    for (int kt = 1; kt < 4; ++kt)
#pragma unroll
      for (int mt = 0; mt < 2; ++mt)
#pragma unroll
        for (int bt = 0; bt < 2; ++bt)
          acc[mt][bt] = mfma16(Wh0[mt][kt], h1f[bt][kt], acc[mt][bt]);
#pragma unroll
    for (int bt = 0; bt < 2; ++bt)
#pragma unroll
      for (int mt = 0; mt < 2; ++mt) {
        u32x2 q = t1q[bt][mt];
        f32x4 a = acc[mt][bt];
        u32x2 w;
        w[0] = pack2(fmaxf(a[0] + blo(q[0]), 0.f), fmaxf(a[1] + bhi(q[0]), 0.f));
        w[1] = pack2(fmaxf(a[2] + blo(q[1]), 0.f), fmaxf(a[3] + bhi(q[1]), 0.f));
        *reinterpret_cast<u32x2*>(slab[0] + wb[bt][mt]) = w;
      }
    // prefetch t1(t+1): stays in flight across both raw barriers (no vmcnt drain)
    {
      int i0 = xs[s0 * 33 + t + 1], i1 = xs[s1 * 33 + t + 1];
      const u32x2* p0 = reinterpret_cast<const u32x2*>(T1p + (size_t)i0 * 64 + jbase);
      const u32x2* p1 = reinterpret_cast<const u32x2*>(T1p + (size_t)i1 * 64 + jbase);
      t1q[0][0] = p0[0]; t1q[0][1] = p0[1];
      t1q[1][0] = p1[0]; t1q[1][1] = p1[1];
    }
    asm volatile("s_waitcnt lgkmcnt(0)" ::: "memory");
    __builtin_amdgcn_s_barrier();
#pragma unroll
    for (int bt = 0; bt < 2; ++bt)
#pragma unroll
      for (int kt = 0; kt < 4; ++kt)
        h1f[bt][kt] = *reinterpret_cast<const short8*>(slab[0] + rb[bt][kt]);

    // phase B: h2_t = relu(bsum + Wi1·h1_t + Wh1·h2_{t-1})
#pragma unroll
    for (int mt = 0; mt < 2; ++mt)
#pragma unroll
      for (int bt = 0; bt < 2; ++bt)
        acc[mt][bt] = (f32x4){blo(bsumP[mt][0]), bhi(bsumP[mt][0]),
                              blo(bsumP[mt][1]), bhi(bsumP[mt][1])};
#pragma unroll
    for (int kt = 0; kt < 4; ++kt)
#pragma unroll
      for (int mt = 0; mt < 2; ++mt)
#pragma unroll
        for (int bt = 0; bt < 2; ++bt) {
          acc[mt][bt] = mfma16(Wi1[mt][kt], h1f[bt][kt], acc[mt][bt]);
          acc[mt][bt] = mfma16(Wh1[mt][kt], h2f[bt][kt], acc[mt][bt]);
        }
    if (t < Sd - 1) {
#pragma unroll
      for (int bt = 0; bt < 2; ++bt)
#pragma unroll
        for (int mt = 0; mt < 2; ++mt) {
          f32x4 a = acc[mt][bt];
          u32x2 w;
          w[0] = pack2(fmaxf(a[0], 0.f), fmaxf(a[1], 0.f));
          w[1] = pack2(fmaxf(a[2], 0.f), fmaxf(a[3], 0.f));
          *reinterpret_cast<u32x2*>(slab[1] + wb[bt][mt]) = w;
        }
      asm volatile("s_waitcnt lgkmcnt(0)" ::: "memory");
      __builtin_amdgcn_s_barrier();
#pragma unroll
      for (int bt = 0; bt < 2; ++bt)
#pragma unroll
        for (int kt = 0; kt < 4; ++kt)
          h2f[bt][kt] = *reinterpret_cast<const short8*>(slab[1] + rb[bt][kt]);
    }
  }

  // ---- epilogue: acc = pre-relu h2_31; s1/s2 dots, reduce over lg then ws
  float p1[2] = {0.f, 0.f}, p2[2] = {0.f, 0.f};
#pragma unroll
  for (int mt = 0; mt < 2; ++mt) {
    const float4 w1 = *reinterpret_cast<const float4*>(pred_W + 32 * ws + 16 * mt + 4 * lg);
    const float4 w2 = *reinterpret_cast<const float4*>(pred_W + Hd + 32 * ws + 16 * mt + 4 * lg);
#pragma unroll
    for (int bt = 0; bt < 2; ++bt) {
      f32x4 a = acc[mt][bt];
      float a0 = fmaxf(a[0], 0.f), a1 = fmaxf(a[1], 0.f);
      float a2 = fmaxf(a[2], 0.f), a3 = fmaxf(a[3], 0.f);
      p1[bt] += a0 * w1.x + a1 * w1.y + a2 * w1.z + a3 * w1.w;
      p2[bt] += a0 * w2.x + a1 * w2.y + a2 * w2.z + a3 * w2.w;
    }
  }
#pragma unroll
  for (int bt = 0; bt < 2; ++bt) {
    p1[bt] += __shfl_xor(p1[bt], 16); p1[bt] += __shfl_xor(p1[bt], 32);
    p2[bt] += __shfl_xor(p2[bt], 16); p2[bt] += __shfl_xor(p2[bt], 32);
  }
  if (lg == 0) {
#pragma unroll
    for (int bt = 0; bt < 2; ++bt) {
      sred[ws][bt * 16 + l15][0] = p1[bt];
      sred[ws][bt * 16 + l15][1] = p2[bt];
    }
  }
  __syncthreads();
  if (tid < 64) {
    int nl = tid >> 1, st = tid & 1;
    float v = sred[0][nl][st] + sred[1][nl][st] + sred[2][nl][st] + sred[3][nl][st];
    sbuf[st * 16384 + seq0 + nl] = v;
  }
}

// ---------------------------------------------------------------------------
// K3: out[b,r,c] = s1 + rowsum_c(s2) + colsum_r(s2) - 2*s2 + pred_b
// ---------------------------------------------------------------------------
__global__ __launch_bounds__(1024) void k_final(const float* __restrict__ sbuf,
                                                const float* __restrict__ pred_b,
                                                float* __restrict__ out) {
  __shared__ float s2s[64][65];
  __shared__ float rowS[64], colS[64];
  const int b = blockIdx.x, tid = threadIdx.x;
  const float* s1g = sbuf + b * 4096;
  const float* s2g = sbuf + 16384 + b * 4096;
#pragma unroll
  for (int i = 0; i < 4; ++i) {
    int j = tid + i * 1024;
    s2s[j >> 6][j & 63] = s2g[j];
  }
  __syncthreads();
  if (tid < 64) {
    float s = 0.f;
    for (int cc = 0; cc < 64; ++cc) s += s2s[tid][cc];
    rowS[tid] = s;
  } else if (tid < 128) {
    int cc = tid - 64;
    float s = 0.f;
    for (int r = 0; r < 64; ++r) s += s2s[r][cc];
    colS[cc] = s;
  }
  __syncthreads();
  const float pb = pred_b[0];
#pragma unroll
  for (int i = 0; i < 4; ++i) {
    int j = tid + i * 1024;
    int r = j >> 6, cc = j & 63;
    out[b * 4096 + j] = s1g[j] + rowS[r] + colS[cc] - 2.f * s2s[r][cc] + pb;
  }
}

// ---------------------------------------------------------------------------
extern "C" void kernel_launch(void* const* d_in, const int* in_sizes, int n_in,
                              void* d_out, int out_size, void* d_ws,
                              size_t ws_size, hipStream_t stream) {
  const int* x = (const int*)d_in[0];
  const float* embed = (const float*)d_in[1];
  const float* W_ih = (const float*)d_in[2];
  const float* W_hh = (const float*)d_in[3];
  const float* b_ih = (const float*)d_in[4];
  const float* b_hh = (const float*)d_in[5];
  const float* pred_W = (const float*)d_in[6];
  const float* pred_b = (const float*)d_in[7];

  // ws layout: T1p (7,680,000 B) | sbuf (131,072 B)
  unsigned int* T1p = (unsigned int*)d_ws;
  float* sbuf = (float*)((char*)d_ws + (size_t)VROWS * 256);
  float* out = (float*)d_out;

  k_t1p<<<256, 256, 0, stream>>>(embed, W_ih, b_ih, b_hh, T1p);
  k_rnn<<<512, 256, 0, stream>>>(x, T1p, W_ih, W_hh, b_ih, b_hh, pred_W, sbuf);
  k_final<<<4, 1024, 0, stream>>>(sbuf, pred_b, out);
}